// Round 6
// baseline (6802.982 us; speedup 1.0000x reference)
//
#include <hip/hip_runtime.h>
#include <cstdint>
#include <math.h>

// ConvDBN: 2-layer conv-RBM with Gumbel-max multinomial pooling.
// Numerics (verified passing R1-R5 at absmax 0.0039 = pure quantization, zero
// winner flips): conv in f64, per-acc summation order (ic asc, patch row asc,
// patch col asc); RNG: JAX threefry2x32 partitionable split (child i =
// threefry(key,(0,i))), 32-bit draw = o0^o1, gumbel f32 rounding points exact;
// fast_log/fast_exp (~1e-13) safe vs argmax gaps.
// R6: l2 lane mapping ph in {0,2} for quarter-wave lanes 0-15, {1,3} for 16-31
// -> hs ds_read_b64 residues (4ph+3bw) mod 16 cover ALL 16 bank pairs
// ({3bw} and {3bw+8} are complements) => conflict-free without padding (R5's
// ph in {0,1} covered only 12 -> 2.5e8 conflict cycles). 512 threads, 16 oc
// per block, ic-chunk 2, weights f32 in LDS (cvt on reg-load): LDS 41.3 KB ->
// 2 blocks/CU = 16 waves/CU (50% occupancy, was 22%).

#define EPS_D 1e-8
#define INV_SIGMA2 (1.0 / (0.2 * 0.2))

__host__ __device__ __forceinline__ void threefry2x32(
    uint32_t k0, uint32_t k1, uint32_t x0, uint32_t x1,
    uint32_t* o0, uint32_t* o1) {
  const uint32_t ks0 = k0, ks1 = k1, ks2 = k0 ^ k1 ^ 0x1BD11BDAu;
  x0 += ks0; x1 += ks1;
#define TF_R(r) { x0 += x1; x1 = (x1 << (r)) | (x1 >> (32 - (r))); x1 ^= x0; }
  TF_R(13) TF_R(15) TF_R(26) TF_R(6)
  x0 += ks1; x1 += ks2 + 1u;
  TF_R(17) TF_R(29) TF_R(16) TF_R(24)
  x0 += ks2; x1 += ks0 + 2u;
  TF_R(13) TF_R(15) TF_R(26) TF_R(6)
  x0 += ks0; x1 += ks1 + 3u;
  TF_R(17) TF_R(29) TF_R(16) TF_R(24)
  x0 += ks1; x1 += ks2 + 4u;
  TF_R(13) TF_R(15) TF_R(26) TF_R(6)
  x0 += ks2; x1 += ks0 + 5u;
#undef TF_R
  *o0 = x0; *o1 = x1;
}

__device__ __forceinline__ double fast_log(double x) {
  long long ib = __double_as_longlong(x);
  int e = (int)((ib >> 52) & 0x7ff) - 1023;
  double r = __longlong_as_double((ib & 0xfffffffffffffLL) | 0x3ff0000000000000LL);
  if (r > 1.4142135623730951) { r *= 0.5; e += 1; }
  double s = (r - 1.0) / (r + 1.0);
  double s2 = s * s;
  double t = fma(s2, fma(s2, fma(s2, fma(s2, fma(s2, fma(s2,
      1.0/15.0, 1.0/13.0), 1.0/11.0), 1.0/9.0), 1.0/7.0), 1.0/5.0), 1.0/3.0);
  double lr = fma(2.0 * s * s2, t, 2.0 * s);
  return fma((double)e, 0.6931471805599453, lr);
}

__device__ __forceinline__ double fast_exp(double x) {
  double nd = rint(x * 1.4426950408889634);
  double f = fma(nd, -0.6931471803691238, x);
  f = fma(nd, -1.9082149292705877e-10, f);
  double p = 2.505210838544172e-8;
  p = fma(p, f, 2.755731922398589e-7);
  p = fma(p, f, 2.7557319223985893e-6);
  p = fma(p, f, 2.48015873015873e-5);
  p = fma(p, f, 1.984126984126984e-4);
  p = fma(p, f, 1.3888888888888889e-3);
  p = fma(p, f, 8.333333333333333e-3);
  p = fma(p, f, 4.1666666666666664e-2);
  p = fma(p, f, 0.16666666666666666);
  p = fma(p, f, 0.5);
  p = fma(p, f, 1.0);
  p = fma(p, f, 1.0);
  return ldexp(p, (int)nd);
}

__device__ __forceinline__ double gumbel_pool9(const double (&acc)[9],
                                               double bb, uint64_t base,
                                               uint32_t kp0, uint32_t kp1) {
  double bestv = -1e308, bA = 1.0, bQ = 0.0;
#pragma unroll
  for (int k = 0; k < 9; ++k) {
    double pre = (acc[k] + bb) * INV_SIGMA2;
    double q = fast_exp(-fabs(pre));
    double A = pre >= 0.0 ? 1.0 : q;          // p = A/(1+q)
    double opq = 1.0 + q;
    double L = fast_log(fma(EPS_D, opq, A)) - fast_log(opq);
    uint32_t o0, o1;
    uint64_t idx = base + (uint64_t)k;
    threefry2x32(kp0, kp1, (uint32_t)(idx >> 32), (uint32_t)idx, &o0, &o1);
    uint32_t bits = o0 ^ o1;
    float u = __uint_as_float((bits >> 9) | 0x3f800000u) - 1.0f;
    if (u == 0.0f) u = 1.17549435e-38f;
    float lg1 = (float)fast_log((double)u);
    double lg2 = fast_log(-(double)lg1);
    float gf = -(float)lg2;
    double v = L + (double)gf;
    if (v > bestv) { bestv = v; bA = A; bQ = q; }   // first-occurrence argmax
  }
  return bA / (1.0 + bQ);
}

// Vertical output pair (pooled rows bh0, bh0+1 at fixed bw). Patch = 12 rows x
// 9 cols starting at xb. All indices literal after unroll; w flat [49] in VGPRs.
template <int LDSTRIDE>
__device__ __forceinline__ void conv_pair(const double* __restrict__ xb,
                                          const double (&w)[49],
                                          double (&a0)[9], double (&a1)[9]) {
#pragma unroll
  for (int pr = 0; pr < 12; ++pr) {
    double xr[9];
#pragma unroll
    for (int c = 0; c < 9; ++c) xr[c] = xb[pr * LDSTRIDE + c];
#pragma unroll
    for (int ki = 0; ki < 3; ++ki) {
      const int u0 = pr - ki;
      if (u0 >= 0 && u0 <= 6) {
#pragma unroll
        for (int kj = 0; kj < 3; ++kj)
#pragma unroll
          for (int v = 0; v < 7; ++v)
            a0[ki * 3 + kj] = fma(xr[kj + v], w[u0 * 7 + v], a0[ki * 3 + kj]);
      }
      const int u1 = pr - 3 - ki;
      if (u1 >= 0 && u1 <= 6) {
#pragma unroll
        for (int kj = 0; kj < 3; ++kj)
#pragma unroll
          for (int v = 0; v < 7; ++v)
            a1[ki * 3 + kj] = fma(xr[kj + v], w[u1 * 7 + v], a1[ki * 3 + kj]);
      }
    }
  }
}

// ---------------- Layer 1 ---------------- (unchanged from R5)
__global__ __launch_bounds__(256, 2) void l1_kernel(
    const float* __restrict__ x, const float* __restrict__ W1,
    const float* __restrict__ b1, double* __restrict__ h1,
    uint32_t kp0, uint32_t kp1) {
  const int oc   = blockIdx.x;   // 96
  const int b    = blockIdx.y;   // 64
  const int half = blockIdx.z;   // 2
  const int t = threadIdx.x;

  __shared__ double xs[54 * 97];   // 41,904 B

  const int p0 = 14 * half;
  const bool active = t < 240;
  const int q = t / 30, bw = t - q * 30;   // q 0..7 vertical pair
  const double* xb = xs + (6 * q) * 97 + 3 * bw;

  double a0[9] = {}, a1[9] = {};
  double w[49];

#pragma unroll 1
  for (int ic = 0; ic < 3; ++ic) {
    __syncthreads();
    {
      const float* __restrict__ src = x + ((size_t)b * 3 + ic) * 9216 + (3 * p0) * 96;
#pragma unroll
      for (int k = 0; k < 21; ++k) {
        int j = t + 256 * k;
        if (j < 5184) {
          int r = j / 96, c = j - r * 96;
          xs[r * 97 + c] = (double)src[j];
        }
      }
    }
    __syncthreads();
    {
      const float* __restrict__ wsrc = W1 + (oc * 3 + ic) * 49;  // block-uniform
#pragma unroll
      for (int j = 0; j < 49; ++j) w[j] = (double)wsrc[j];
    }
    if (active) conv_pair<97>(xb, w, a0, a1);
  }

  if (active) {
    const double bb = (double)b1[oc];
    const int bh0 = p0 + 2 * q;
#pragma unroll
    for (int j = 0; j < 2; ++j) {
      const int pos = (bh0 + j) * 30 + bw;
      const uint64_t base = ((uint64_t)((b * 96 + oc) * 900 + pos)) * 9ull;
      double pooled = gumbel_pool9(j ? a1 : a0, bb, base, kp0, kp1);
      h1[(size_t)(b * 96 + oc) * 900 + pos] = pooled;
    }
  }
}

// ---------------- Layer 2 ----------------
// Block = (oc-tile of 16, b); 512 threads = 16 oc (quarter-wave-uniform) x
// 32 lanes (8 bw x 4 row-pairs), 2 vertical outputs per thread.
// Lane map: bw = li&7; ph = 2*((li>>3)&1) + (li>>4)  => lanes 0-15 have
// ph in {0,2} (residues 3bw, 3bw+8: all 16 bank pairs), lanes 16-31 ph in
// {1,3} (3bw+4, 3bw+12: all 16) -> conflict-free ds_read_b64, stride 30.
// ic-chunk 2, double-buffered: hs via global_load_lds 16B DMA (contiguous),
// weights f32 in LDS (cvt at reg-load). One barrier per chunk.
__global__ __launch_bounds__(512, 4) void l2_kernel(
    const double* __restrict__ h1, const float* __restrict__ W2,
    const float* __restrict__ b2, float* __restrict__ out,
    uint32_t kp0, uint32_t kp1) {
  const int octile = blockIdx.x;  // 12
  const int b      = blockIdx.y;  // 64
  const int t = threadIdx.x;
  const int wave = t >> 6;
  const int oc_local = t >> 5;            // 0..15, quarter-wave uniform
  const int li = t & 31;
  const int bw = li & 7;
  const int ph = 2 * ((li >> 3) & 1) + (li >> 4);   // 0,2 | 1,3
  const int bh0 = 2 * ph;
  const int oc = octile * 16 + oc_local;

  __shared__ double hs[2][1800];      // 28,800 B
  __shared__ float  wsf[2][1568];     // 12,544 B

  const double* __restrict__ hb = h1 + (size_t)b * 86400;
  const float* __restrict__ wg = W2 + (size_t)octile * 16 * 4704;

  double a0[9] = {}, a1[9] = {};
  double w[49];

  auto stage = [&](int c, int buf) {
    // hs: 1800 doubles = 900 x 16B contiguous; DMA dest = wave base + lane*16.
    const char* gsrc = (const char*)(hb + (size_t)c * 1800);
#pragma unroll
    for (int p = 0; p < 2; ++p) {
      int elt = p * 512 + t;
      if (elt < 900) {
        __builtin_amdgcn_global_load_lds(
            (const __attribute__((address_space(1))) void*)(gsrc + (size_t)elt * 16),
            (__attribute__((address_space(3))) void*)((char*)&hs[buf][0] +
                                                      (size_t)(p * 512 + wave * 64) * 16),
            16, 0, 0);
      }
    }
    // weights f32: 16 oc x 2 ic x 49 = 1568, layout [oi][cc*49+j].
#pragma unroll
    for (int p = 0; p < 4; ++p) {
      int j = p * 512 + t;
      if (j < 1568) {
        int oi = j / 98, rem = j - oi * 98;
        wsf[buf][j] = wg[(size_t)oi * 4704 + c * 98 + rem];
      }
    }
  };

  stage(0, 0);
#pragma unroll 1
  for (int c = 0; c < 48; ++c) {
    __syncthreads();   // drains DMA for buf c&1; all waves done with other buf
    if (c + 1 < 48) stage(c + 1, (c + 1) & 1);
#pragma unroll 1
    for (int cc = 0; cc < 2; ++cc) {
      const float* __restrict__ wsrc = &wsf[c & 1][oc_local * 98 + cc * 49];
#pragma unroll
      for (int j = 0; j < 49; ++j) w[j] = (double)wsrc[j];   // bcast + cvt
      const double* xb = &hs[c & 1][cc * 900 + (6 * ph) * 30 + 3 * bw];
      conv_pair<30>(xb, w, a0, a1);
    }
  }

  const double bb = (double)b2[oc];
#pragma unroll
  for (int j = 0; j < 2; ++j) {
    const int bh = bh0 + j;
    const uint64_t base = ((uint64_t)(((b * 192 + oc) * 8 + bh) * 8 + bw)) * 9ull;
    double pooled = gumbel_pool9(j ? a1 : a0, bb, base, kp0, kp1);
    out[(size_t)(b * 192 + oc) * 64 + bh * 8 + bw] = (float)pooled;
  }
}

extern "C" void kernel_launch(void* const* d_in, const int* in_sizes, int n_in,
                              void* d_out, int out_size, void* d_ws,
                              size_t ws_size, hipStream_t stream) {
  const float* x  = (const float*)d_in[0];   // [64,3,96,96]
  const float* W1 = (const float*)d_in[1];   // [96,3,7,7]
  const float* b1 = (const float*)d_in[2];   // [96]
  const float* W2 = (const float*)d_in[3];   // [192,96,7,7]
  const float* b2 = (const float*)d_in[4];   // [192]
  float* out = (float*)d_out;                // [64,192,8,8]
  double* h1 = (double*)d_ws;                // 5,529,600 f64 = 44.2 MB

  uint32_t kp1a, kp1b, kp2a, kp2b;
  threefry2x32(0u, 42u, 0u, 0u, &kp1a, &kp1b);
  threefry2x32(0u, 42u, 0u, 1u, &kp2a, &kp2b);

  l1_kernel<<<dim3(96, 64, 2), 256, 0, stream>>>(x, W1, b1, h1, kp1a, kp1b);
  l2_kernel<<<dim3(12, 64), 512, 0, stream>>>(h1, W2, b2, out, kp2a, kp2b);
}

// Round 7
// 2063.513 us; speedup vs baseline: 3.2968x; 3.2968x over previous
//
#include <hip/hip_runtime.h>
#include <cstdint>
#include <math.h>

// ConvDBN: 2-layer conv-RBM with Gumbel-max multinomial pooling.
// Numerics (verified passing R1-R6 at absmax 0.0039 = pure quantization, zero
// winner flips): conv in f64, per-acc summation order (ic asc, patch row asc,
// patch col asc); RNG: JAX threefry2x32 partitionable split (child i =
// threefry(key,(0,i))), 32-bit draw = o0^o1, gumbel f32 rounding points exact;
// fast_log/fast_exp (~1e-13) safe vs argmax gaps.
// R7 = R5's register budget + R6's lane map (the two proven wins, combined):
//   - 256 thr, __launch_bounds__(256,2): reg cap ~256 -> w[49] f64 lives in
//     VGPR/AGPR, NO spills (R6's (512,4) cap=128 spilled w -> 15.7 GB scratch
//     writes, 6.35 ms).
//   - lane map bw=li&7, ph=2*((li>>3)&1)+(li>>4): hs ds_read_b64 residues
//     (4ph+3bw) mod 16 cover all 16 bank pairs per quarter-wave -> 0 conflicts
//     (R6-verified).
//   - weights f64 in LDS (cvt once at staging), hs via 16B global_load_lds DMA
//     double-buffer, one barrier per ic-chunk of 2.

#define EPS_D 1e-8
#define INV_SIGMA2 (1.0 / (0.2 * 0.2))

__host__ __device__ __forceinline__ void threefry2x32(
    uint32_t k0, uint32_t k1, uint32_t x0, uint32_t x1,
    uint32_t* o0, uint32_t* o1) {
  const uint32_t ks0 = k0, ks1 = k1, ks2 = k0 ^ k1 ^ 0x1BD11BDAu;
  x0 += ks0; x1 += ks1;
#define TF_R(r) { x0 += x1; x1 = (x1 << (r)) | (x1 >> (32 - (r))); x1 ^= x0; }
  TF_R(13) TF_R(15) TF_R(26) TF_R(6)
  x0 += ks1; x1 += ks2 + 1u;
  TF_R(17) TF_R(29) TF_R(16) TF_R(24)
  x0 += ks2; x1 += ks0 + 2u;
  TF_R(13) TF_R(15) TF_R(26) TF_R(6)
  x0 += ks0; x1 += ks1 + 3u;
  TF_R(17) TF_R(29) TF_R(16) TF_R(24)
  x0 += ks1; x1 += ks2 + 4u;
  TF_R(13) TF_R(15) TF_R(26) TF_R(6)
  x0 += ks2; x1 += ks0 + 5u;
#undef TF_R
  *o0 = x0; *o1 = x1;
}

__device__ __forceinline__ double fast_log(double x) {
  long long ib = __double_as_longlong(x);
  int e = (int)((ib >> 52) & 0x7ff) - 1023;
  double r = __longlong_as_double((ib & 0xfffffffffffffLL) | 0x3ff0000000000000LL);
  if (r > 1.4142135623730951) { r *= 0.5; e += 1; }
  double s = (r - 1.0) / (r + 1.0);
  double s2 = s * s;
  double t = fma(s2, fma(s2, fma(s2, fma(s2, fma(s2, fma(s2,
      1.0/15.0, 1.0/13.0), 1.0/11.0), 1.0/9.0), 1.0/7.0), 1.0/5.0), 1.0/3.0);
  double lr = fma(2.0 * s * s2, t, 2.0 * s);
  return fma((double)e, 0.6931471805599453, lr);
}

__device__ __forceinline__ double fast_exp(double x) {
  double nd = rint(x * 1.4426950408889634);
  double f = fma(nd, -0.6931471803691238, x);
  f = fma(nd, -1.9082149292705877e-10, f);
  double p = 2.505210838544172e-8;
  p = fma(p, f, 2.755731922398589e-7);
  p = fma(p, f, 2.7557319223985893e-6);
  p = fma(p, f, 2.48015873015873e-5);
  p = fma(p, f, 1.984126984126984e-4);
  p = fma(p, f, 1.3888888888888889e-3);
  p = fma(p, f, 8.333333333333333e-3);
  p = fma(p, f, 4.1666666666666664e-2);
  p = fma(p, f, 0.16666666666666666);
  p = fma(p, f, 0.5);
  p = fma(p, f, 1.0);
  p = fma(p, f, 1.0);
  return ldexp(p, (int)nd);
}

__device__ __forceinline__ double gumbel_pool9(const double (&acc)[9],
                                               double bb, uint64_t base,
                                               uint32_t kp0, uint32_t kp1) {
  double bestv = -1e308, bA = 1.0, bQ = 0.0;
#pragma unroll
  for (int k = 0; k < 9; ++k) {
    double pre = (acc[k] + bb) * INV_SIGMA2;
    double q = fast_exp(-fabs(pre));
    double A = pre >= 0.0 ? 1.0 : q;          // p = A/(1+q)
    double opq = 1.0 + q;
    double L = fast_log(fma(EPS_D, opq, A)) - fast_log(opq);
    uint32_t o0, o1;
    uint64_t idx = base + (uint64_t)k;
    threefry2x32(kp0, kp1, (uint32_t)(idx >> 32), (uint32_t)idx, &o0, &o1);
    uint32_t bits = o0 ^ o1;
    float u = __uint_as_float((bits >> 9) | 0x3f800000u) - 1.0f;
    if (u == 0.0f) u = 1.17549435e-38f;
    float lg1 = (float)fast_log((double)u);
    double lg2 = fast_log(-(double)lg1);
    float gf = -(float)lg2;
    double v = L + (double)gf;
    if (v > bestv) { bestv = v; bA = A; bQ = q; }   // first-occurrence argmax
  }
  return bA / (1.0 + bQ);
}

// Vertical output pair (pooled rows bh0, bh0+1 at fixed bw). Patch = 12 rows x
// 9 cols starting at xb. All indices literal after unroll; w flat [49] in regs.
template <int LDSTRIDE>
__device__ __forceinline__ void conv_pair(const double* __restrict__ xb,
                                          const double (&w)[49],
                                          double (&a0)[9], double (&a1)[9]) {
#pragma unroll
  for (int pr = 0; pr < 12; ++pr) {
    double xr[9];
#pragma unroll
    for (int c = 0; c < 9; ++c) xr[c] = xb[pr * LDSTRIDE + c];
#pragma unroll
    for (int ki = 0; ki < 3; ++ki) {
      const int u0 = pr - ki;
      if (u0 >= 0 && u0 <= 6) {
#pragma unroll
        for (int kj = 0; kj < 3; ++kj)
#pragma unroll
          for (int v = 0; v < 7; ++v)
            a0[ki * 3 + kj] = fma(xr[kj + v], w[u0 * 7 + v], a0[ki * 3 + kj]);
      }
      const int u1 = pr - 3 - ki;
      if (u1 >= 0 && u1 <= 6) {
#pragma unroll
        for (int kj = 0; kj < 3; ++kj)
#pragma unroll
          for (int v = 0; v < 7; ++v)
            a1[ki * 3 + kj] = fma(xr[kj + v], w[u1 * 7 + v], a1[ki * 3 + kj]);
      }
    }
  }
}

// ---------------- Layer 1 ---------------- (unchanged from R5/R6)
__global__ __launch_bounds__(256, 2) void l1_kernel(
    const float* __restrict__ x, const float* __restrict__ W1,
    const float* __restrict__ b1, double* __restrict__ h1,
    uint32_t kp0, uint32_t kp1) {
  const int oc   = blockIdx.x;   // 96
  const int b    = blockIdx.y;   // 64
  const int half = blockIdx.z;   // 2
  const int t = threadIdx.x;

  __shared__ double xs[54 * 97];   // 41,904 B

  const int p0 = 14 * half;
  const bool active = t < 240;
  const int q = t / 30, bw = t - q * 30;   // q 0..7 vertical pair
  const double* xb = xs + (6 * q) * 97 + 3 * bw;

  double a0[9] = {}, a1[9] = {};
  double w[49];

#pragma unroll 1
  for (int ic = 0; ic < 3; ++ic) {
    __syncthreads();
    {
      const float* __restrict__ src = x + ((size_t)b * 3 + ic) * 9216 + (3 * p0) * 96;
#pragma unroll
      for (int k = 0; k < 21; ++k) {
        int j = t + 256 * k;
        if (j < 5184) {
          int r = j / 96, c = j - r * 96;
          xs[r * 97 + c] = (double)src[j];
        }
      }
    }
    __syncthreads();
    {
      const float* __restrict__ wsrc = W1 + (oc * 3 + ic) * 49;  // block-uniform
#pragma unroll
      for (int j = 0; j < 49; ++j) w[j] = (double)wsrc[j];
    }
    if (active) conv_pair<97>(xb, w, a0, a1);
  }

  if (active) {
    const double bb = (double)b1[oc];
    const int bh0 = p0 + 2 * q;
#pragma unroll
    for (int j = 0; j < 2; ++j) {
      const int pos = (bh0 + j) * 30 + bw;
      const uint64_t base = ((uint64_t)((b * 96 + oc) * 900 + pos)) * 9ull;
      double pooled = gumbel_pool9(j ? a1 : a0, bb, base, kp0, kp1);
      h1[(size_t)(b * 96 + oc) * 900 + pos] = pooled;
    }
  }
}

// ---------------- Layer 2 ----------------
// Block = (oc-tile of 8, b); 256 threads = 8 oc (half-wave-uniform) x 32 lanes
// (8 bw x 4 row-pairs), 2 vertical outputs per thread.
// Lane map (R6-verified conflict-free): bw=li&7, ph=2*((li>>3)&1)+(li>>4).
// ic-chunk 2 double-buffered: hs via global_load_lds 16B DMA, wsd f64 in LDS.
// One barrier per chunk; DMA for c+1 overlaps compute of c.
__global__ __launch_bounds__(256, 2) void l2_kernel(
    const double* __restrict__ h1, const float* __restrict__ W2,
    const float* __restrict__ b2, float* __restrict__ out,
    uint32_t kp0, uint32_t kp1) {
  const int octile = blockIdx.x;  // 24
  const int b      = blockIdx.y;  // 64
  const int t = threadIdx.x;
  const int wave = t >> 6;
  const int oc_local = t >> 5;            // 0..7, half-wave uniform
  const int li = t & 31;
  const int bw = li & 7;
  const int ph = 2 * ((li >> 3) & 1) + (li >> 4);   // lanes 0-15: {0,2}; 16-31: {1,3}
  const int bh0 = 2 * ph;
  const int oc = octile * 8 + oc_local;

  __shared__ double hs[2][1800];      // 28,800 B
  __shared__ double wsd[2][784];      // 12,544 B  (8 oc x 2 ic x 49, f64)

  const double* __restrict__ hb = h1 + (size_t)b * 86400;
  const float* __restrict__ wg = W2 + (size_t)octile * 8 * 4704;

  double a0[9] = {}, a1[9] = {};
  double w[49];

  auto stage = [&](int c, int buf) {
    // hs: 1800 doubles = 900 x 16B contiguous; DMA dest = wave base + lane*16.
    const char* gsrc = (const char*)(hb + (size_t)c * 1800);
#pragma unroll
    for (int p = 0; p < 4; ++p) {
      int elt = p * 256 + t;
      if (elt < 900) {
        __builtin_amdgcn_global_load_lds(
            (const __attribute__((address_space(1))) void*)(gsrc + (size_t)elt * 16),
            (__attribute__((address_space(3))) void*)((char*)&hs[buf][0] +
                                                      (size_t)(p * 256 + wave * 64) * 16),
            16, 0, 0);
      }
    }
    // weights: 8 oc x 98 f32 -> f64, layout [oi][cc*49+j].
#pragma unroll
    for (int p = 0; p < 4; ++p) {
      int j = p * 256 + t;
      if (j < 784) {
        int oi = j / 98, rem = j - oi * 98;
        wsd[buf][j] = (double)wg[(size_t)oi * 4704 + c * 98 + rem];
      }
    }
  };

  stage(0, 0);
#pragma unroll 1
  for (int c = 0; c < 48; ++c) {
    __syncthreads();   // drains DMA for buf c&1; all waves done with other buf
    if (c + 1 < 48) stage(c + 1, (c + 1) & 1);
#pragma unroll 1
    for (int cc = 0; cc < 2; ++cc) {
      const double* __restrict__ wsrc = &wsd[c & 1][oc_local * 98 + cc * 49];
#pragma unroll
      for (int j = 0; j < 49; ++j) w[j] = wsrc[j];   // LDS broadcast
      const double* xb = &hs[c & 1][cc * 900 + (6 * ph) * 30 + 3 * bw];
      conv_pair<30>(xb, w, a0, a1);
    }
  }

  const double bb = (double)b2[oc];
#pragma unroll
  for (int j = 0; j < 2; ++j) {
    const int bh = bh0 + j;
    const uint64_t base = ((uint64_t)(((b * 192 + oc) * 8 + bh) * 8 + bw)) * 9ull;
    double pooled = gumbel_pool9(j ? a1 : a0, bb, base, kp0, kp1);
    out[(size_t)(b * 192 + oc) * 64 + bh * 8 + bw] = (float)pooled;
  }
}

extern "C" void kernel_launch(void* const* d_in, const int* in_sizes, int n_in,
                              void* d_out, int out_size, void* d_ws,
                              size_t ws_size, hipStream_t stream) {
  const float* x  = (const float*)d_in[0];   // [64,3,96,96]
  const float* W1 = (const float*)d_in[1];   // [96,3,7,7]
  const float* b1 = (const float*)d_in[2];   // [96]
  const float* W2 = (const float*)d_in[3];   // [192,96,7,7]
  const float* b2 = (const float*)d_in[4];   // [192]
  float* out = (float*)d_out;                // [64,192,8,8]
  double* h1 = (double*)d_ws;                // 5,529,600 f64 = 44.2 MB

  uint32_t kp1a, kp1b, kp2a, kp2b;
  threefry2x32(0u, 42u, 0u, 0u, &kp1a, &kp1b);
  threefry2x32(0u, 42u, 0u, 1u, &kp2a, &kp2b);

  l1_kernel<<<dim3(96, 64, 2), 256, 0, stream>>>(x, W1, b1, h1, kp1a, kp1b);
  l2_kernel<<<dim3(24, 64), 256, 0, stream>>>(h1, W2, b2, out, kp2a, kp2b);
}

// Round 8
// 1984.519 us; speedup vs baseline: 3.4280x; 1.0398x over previous
//
#include <hip/hip_runtime.h>
#include <cstdint>
#include <math.h>

// ConvDBN: 2-layer conv-RBM with Gumbel-max multinomial pooling.
// Numerics (verified passing R1-R7 at absmax 0.0039 = pure quantization, zero
// winner flips): conv in f64, per-acc summation order (ic asc, patch row asc,
// patch col asc); RNG: JAX threefry2x32 partitionable split (child i =
// threefry(key,(0,i))), 32-bit draw = o0^o1, gumbel f32 rounding points exact;
// fast_log/fast_exp (~1e-13) safe vs argmax gaps.
// R8: occupancy push (R7 was stall-bound at ~2 blocks/CU, LDS 41.5 KB binding):
//   - l2 ic-chunk 2 -> 1 (same DMA double-buffer + one barrier per chunk):
//     LDS 20.7 KB -> 4-5 resident blocks/CU. Inner conv identical to R7
//     (f64 wsd in LDS, w[49] reg loads) -- proven no-spill at VGPR 96.
//   - launch_bounds(256,3): VGPR cap 170 >> 96 used (NOT 4/cap-128: that was
//     R6's spill trap with cvt-materialization).
//   - l1 stages x as f32 (cvt f64 on read -- exact, order unchanged) via 16B
//     global_load_lds DMA, unpadded stride 96 (f32 banks 3bw+c mod 32,
//     gcd(3,32)=1 -> conflict-free): LDS 41.9 -> 20.7 KB.

#define EPS_D 1e-8
#define INV_SIGMA2 (1.0 / (0.2 * 0.2))

__host__ __device__ __forceinline__ void threefry2x32(
    uint32_t k0, uint32_t k1, uint32_t x0, uint32_t x1,
    uint32_t* o0, uint32_t* o1) {
  const uint32_t ks0 = k0, ks1 = k1, ks2 = k0 ^ k1 ^ 0x1BD11BDAu;
  x0 += ks0; x1 += ks1;
#define TF_R(r) { x0 += x1; x1 = (x1 << (r)) | (x1 >> (32 - (r))); x1 ^= x0; }
  TF_R(13) TF_R(15) TF_R(26) TF_R(6)
  x0 += ks1; x1 += ks2 + 1u;
  TF_R(17) TF_R(29) TF_R(16) TF_R(24)
  x0 += ks2; x1 += ks0 + 2u;
  TF_R(13) TF_R(15) TF_R(26) TF_R(6)
  x0 += ks0; x1 += ks1 + 3u;
  TF_R(17) TF_R(29) TF_R(16) TF_R(24)
  x0 += ks1; x1 += ks2 + 4u;
  TF_R(13) TF_R(15) TF_R(26) TF_R(6)
  x0 += ks2; x1 += ks0 + 5u;
#undef TF_R
  *o0 = x0; *o1 = x1;
}

__device__ __forceinline__ double fast_log(double x) {
  long long ib = __double_as_longlong(x);
  int e = (int)((ib >> 52) & 0x7ff) - 1023;
  double r = __longlong_as_double((ib & 0xfffffffffffffLL) | 0x3ff0000000000000LL);
  if (r > 1.4142135623730951) { r *= 0.5; e += 1; }
  double s = (r - 1.0) / (r + 1.0);
  double s2 = s * s;
  double t = fma(s2, fma(s2, fma(s2, fma(s2, fma(s2, fma(s2,
      1.0/15.0, 1.0/13.0), 1.0/11.0), 1.0/9.0), 1.0/7.0), 1.0/5.0), 1.0/3.0);
  double lr = fma(2.0 * s * s2, t, 2.0 * s);
  return fma((double)e, 0.6931471805599453, lr);
}

__device__ __forceinline__ double fast_exp(double x) {
  double nd = rint(x * 1.4426950408889634);
  double f = fma(nd, -0.6931471803691238, x);
  f = fma(nd, -1.9082149292705877e-10, f);
  double p = 2.505210838544172e-8;
  p = fma(p, f, 2.755731922398589e-7);
  p = fma(p, f, 2.7557319223985893e-6);
  p = fma(p, f, 2.48015873015873e-5);
  p = fma(p, f, 1.984126984126984e-4);
  p = fma(p, f, 1.3888888888888889e-3);
  p = fma(p, f, 8.333333333333333e-3);
  p = fma(p, f, 4.1666666666666664e-2);
  p = fma(p, f, 0.16666666666666666);
  p = fma(p, f, 0.5);
  p = fma(p, f, 1.0);
  p = fma(p, f, 1.0);
  return ldexp(p, (int)nd);
}

__device__ __forceinline__ double gumbel_pool9(const double (&acc)[9],
                                               double bb, uint64_t base,
                                               uint32_t kp0, uint32_t kp1) {
  double bestv = -1e308, bA = 1.0, bQ = 0.0;
#pragma unroll
  for (int k = 0; k < 9; ++k) {
    double pre = (acc[k] + bb) * INV_SIGMA2;
    double q = fast_exp(-fabs(pre));
    double A = pre >= 0.0 ? 1.0 : q;          // p = A/(1+q)
    double opq = 1.0 + q;
    double L = fast_log(fma(EPS_D, opq, A)) - fast_log(opq);
    uint32_t o0, o1;
    uint64_t idx = base + (uint64_t)k;
    threefry2x32(kp0, kp1, (uint32_t)(idx >> 32), (uint32_t)idx, &o0, &o1);
    uint32_t bits = o0 ^ o1;
    float u = __uint_as_float((bits >> 9) | 0x3f800000u) - 1.0f;
    if (u == 0.0f) u = 1.17549435e-38f;
    float lg1 = (float)fast_log((double)u);
    double lg2 = fast_log(-(double)lg1);
    float gf = -(float)lg2;
    double v = L + (double)gf;
    if (v > bestv) { bestv = v; bA = A; bQ = q; }   // first-occurrence argmax
  }
  return bA / (1.0 + bQ);
}

// Vertical output pair (pooled rows bh0, bh0+1 at fixed bw). Patch = 12 rows x
// 9 cols starting at xb. All indices literal after unroll. T=float source is
// cvt'd to f64 on read (exact, order unchanged).
template <int LDSTRIDE, typename T>
__device__ __forceinline__ void conv_pair(const T* __restrict__ xb,
                                          const double (&w)[49],
                                          double (&a0)[9], double (&a1)[9]) {
#pragma unroll
  for (int pr = 0; pr < 12; ++pr) {
    double xr[9];
#pragma unroll
    for (int c = 0; c < 9; ++c) xr[c] = (double)xb[pr * LDSTRIDE + c];
#pragma unroll
    for (int ki = 0; ki < 3; ++ki) {
      const int u0 = pr - ki;
      if (u0 >= 0 && u0 <= 6) {
#pragma unroll
        for (int kj = 0; kj < 3; ++kj)
#pragma unroll
          for (int v = 0; v < 7; ++v)
            a0[ki * 3 + kj] = fma(xr[kj + v], w[u0 * 7 + v], a0[ki * 3 + kj]);
      }
      const int u1 = pr - 3 - ki;
      if (u1 >= 0 && u1 <= 6) {
#pragma unroll
        for (int kj = 0; kj < 3; ++kj)
#pragma unroll
          for (int v = 0; v < 7; ++v)
            a1[ki * 3 + kj] = fma(xr[kj + v], w[u1 * 7 + v], a1[ki * 3 + kj]);
      }
    }
  }
}

// ---------------- Layer 1 ----------------
// Block = (oc, b, half); 256 threads: t<240 compute (8 vertical pairs x 30 bw).
// xs: f32, 54 rows x stride 96, 20,736 B, staged by 16B global_load_lds DMA
// (contiguous, no padding -- DMA requires lane-ordered dest). Single buffer,
// two barriers per ic (3 ics; drains hidden by 4-5 resident blocks/CU).
__global__ __launch_bounds__(256, 3) void l1_kernel(
    const float* __restrict__ x, const float* __restrict__ W1,
    const float* __restrict__ b1, double* __restrict__ h1,
    uint32_t kp0, uint32_t kp1) {
  const int oc   = blockIdx.x;   // 96
  const int b    = blockIdx.y;   // 64
  const int half = blockIdx.z;   // 2
  const int t = threadIdx.x;
  const int wave = t >> 6;

  __shared__ float xs[54 * 96];   // 20,736 B

  const int p0 = 14 * half;
  const bool active = t < 240;
  const int q = t / 30, bw = t - q * 30;   // q 0..7 vertical pair
  const float* xb = xs + (6 * q) * 96 + 3 * bw;

  double a0[9] = {}, a1[9] = {};
  double w[49];

#pragma unroll 1
  for (int ic = 0; ic < 3; ++ic) {
    __syncthreads();   // readers of previous ic done
    {
      // 54 rows x 96 f32 = 5184 floats = 1296 x 16B, contiguous in global.
      const char* gsrc = (const char*)(x + ((size_t)b * 3 + ic) * 9216 + (3 * p0) * 96);
#pragma unroll
      for (int p = 0; p < 6; ++p) {
        int elt = p * 256 + t;
        if (elt < 1296) {
          __builtin_amdgcn_global_load_lds(
              (const __attribute__((address_space(1))) void*)(gsrc + (size_t)elt * 16),
              (__attribute__((address_space(3))) void*)((char*)xs +
                                                        (size_t)(p * 256 + wave * 64) * 16),
              16, 0, 0);
        }
      }
    }
    __syncthreads();   // DMA drained (vmcnt(0) before barrier)
    {
      const float* __restrict__ wsrc = W1 + (oc * 3 + ic) * 49;  // block-uniform
#pragma unroll
      for (int j = 0; j < 49; ++j) w[j] = (double)wsrc[j];
    }
    if (active) conv_pair<96, float>(xb, w, a0, a1);
  }

  if (active) {
    const double bb = (double)b1[oc];
    const int bh0 = p0 + 2 * q;
#pragma unroll
    for (int j = 0; j < 2; ++j) {
      const int pos = (bh0 + j) * 30 + bw;
      const uint64_t base = ((uint64_t)((b * 96 + oc) * 900 + pos)) * 9ull;
      double pooled = gumbel_pool9(j ? a1 : a0, bb, base, kp0, kp1);
      h1[(size_t)(b * 96 + oc) * 900 + pos] = pooled;
    }
  }
}

// ---------------- Layer 2 ----------------
// Block = (oc-tile of 8, b); 256 threads = 8 oc (half-wave-uniform) x 32 lanes
// (8 bw x 4 row-pairs), 2 vertical outputs per thread.
// Lane map (R6-verified conflict-free): bw=li&7, ph=2*((li>>3)&1)+(li>>4).
// ic-chunk 1 double-buffered: hs via 16B global_load_lds DMA, wsd f64 in LDS.
// LDS 20.7 KB -> 4-5 resident blocks/CU. One barrier per chunk.
__global__ __launch_bounds__(256, 3) void l2_kernel(
    const double* __restrict__ h1, const float* __restrict__ W2,
    const float* __restrict__ b2, float* __restrict__ out,
    uint32_t kp0, uint32_t kp1) {
  const int octile = blockIdx.x;  // 24
  const int b      = blockIdx.y;  // 64
  const int t = threadIdx.x;
  const int wave = t >> 6;
  const int oc_local = t >> 5;            // 0..7, half-wave uniform
  const int li = t & 31;
  const int bw = li & 7;
  const int ph = 2 * ((li >> 3) & 1) + (li >> 4);   // lanes 0-15: {0,2}; 16-31: {1,3}
  const int bh0 = 2 * ph;
  const int oc = octile * 8 + oc_local;

  __shared__ double hs[2][900];     // 14,400 B
  __shared__ double wsd[2][392];    //  6,272 B  (8 oc x 49, f64)

  const double* __restrict__ hb = h1 + (size_t)b * 86400;
  const float* __restrict__ wg = W2 + (size_t)octile * 8 * 4704;

  double a0[9] = {}, a1[9] = {};
  double w[49];

  auto stage = [&](int c, int buf) {
    // hs: 900 doubles = 450 x 16B contiguous; DMA dest = wave base + lane*16.
    const char* gsrc = (const char*)(hb + (size_t)c * 900);
#pragma unroll
    for (int p = 0; p < 2; ++p) {
      int elt = p * 256 + t;
      if (elt < 450) {
        __builtin_amdgcn_global_load_lds(
            (const __attribute__((address_space(1))) void*)(gsrc + (size_t)elt * 16),
            (__attribute__((address_space(3))) void*)((char*)&hs[buf][0] +
                                                      (size_t)(p * 256 + wave * 64) * 16),
            16, 0, 0);
      }
    }
    // weights: 8 oc x 49 f32 -> f64, layout [oi][j].
#pragma unroll
    for (int p = 0; p < 2; ++p) {
      int j = p * 256 + t;
      if (j < 392) {
        int oi = j / 49, rem = j - oi * 49;
        wsd[buf][j] = (double)wg[(size_t)oi * 4704 + c * 49 + rem];
      }
    }
  };

  stage(0, 0);
#pragma unroll 1
  for (int c = 0; c < 96; ++c) {
    __syncthreads();   // drains DMA for buf c&1; all waves done with other buf
    if (c + 1 < 96) stage(c + 1, (c + 1) & 1);
    {
      const double* __restrict__ wsrc = &wsd[c & 1][oc_local * 49];
#pragma unroll
      for (int j = 0; j < 49; ++j) w[j] = wsrc[j];   // LDS broadcast
      const double* xb = &hs[c & 1][(6 * ph) * 30 + 3 * bw];
      conv_pair<30, double>(xb, w, a0, a1);
    }
  }

  const double bb = (double)b2[oc];
#pragma unroll
  for (int j = 0; j < 2; ++j) {
    const int bh = bh0 + j;
    const uint64_t base = ((uint64_t)(((b * 192 + oc) * 8 + bh) * 8 + bw)) * 9ull;
    double pooled = gumbel_pool9(j ? a1 : a0, bb, base, kp0, kp1);
    out[(size_t)(b * 192 + oc) * 64 + bh * 8 + bw] = (float)pooled;
  }
}

extern "C" void kernel_launch(void* const* d_in, const int* in_sizes, int n_in,
                              void* d_out, int out_size, void* d_ws,
                              size_t ws_size, hipStream_t stream) {
  const float* x  = (const float*)d_in[0];   // [64,3,96,96]
  const float* W1 = (const float*)d_in[1];   // [96,3,7,7]
  const float* b1 = (const float*)d_in[2];   // [96]
  const float* W2 = (const float*)d_in[3];   // [192,96,7,7]
  const float* b2 = (const float*)d_in[4];   // [192]
  float* out = (float*)d_out;                // [64,192,8,8]
  double* h1 = (double*)d_ws;                // 5,529,600 f64 = 44.2 MB

  uint32_t kp1a, kp1b, kp2a, kp2b;
  threefry2x32(0u, 42u, 0u, 0u, &kp1a, &kp1b);
  threefry2x32(0u, 42u, 0u, 1u, &kp2a, &kp2b);

  l1_kernel<<<dim3(96, 64, 2), 256, 0, stream>>>(x, W1, b1, h1, kp1a, kp1b);
  l2_kernel<<<dim3(24, 64), 256, 0, stream>>>(h1, W2, b2, out, kp2a, kp2b);
}

// Round 9
// 1959.762 us; speedup vs baseline: 3.4713x; 1.0126x over previous
//
#include <hip/hip_runtime.h>
#include <cstdint>
#include <math.h>

// ConvDBN: 2-layer conv-RBM with Gumbel-max multinomial pooling.
// Numerics (verified passing R1-R8 at absmax 0.0039 = pure quantization, zero
// winner flips): conv in f64, per-acc summation order (ic asc, kh asc, kw asc);
// RNG: JAX threefry2x32 partitionable split (child i = threefry(key,(0,i))),
// 32-bit draw = o0^o1, gumbel f32 rounding points exact; fast_log/fast_exp
// (~1e-13) safe vs argmax gaps.
// R9: l2 2x2 output blocking -- R8 was dual-pipe-saturated (FMA 0.85 ms, LDS
// ~0.8 ms). 12x12 patch: 72 hs-read insts / 4 outputs (vs 120), waves halved.
// Lane map: quarter-wave = 2 oc x 8 sb of one parity group; sb-sharing lanes
// have identical hs addresses (broadcast), group residues 4sb_h+6sb_w cover
// all 8 even bank-pairs; b128 2-pair span covers all 16 => conflict-free.
// launch_bounds(256,2): reg cap 256 for acc72+w98+xr24 (R6: cap 128 spills).

#define EPS_D 1e-8
#define INV_SIGMA2 (1.0 / (0.2 * 0.2))

__host__ __device__ __forceinline__ void threefry2x32(
    uint32_t k0, uint32_t k1, uint32_t x0, uint32_t x1,
    uint32_t* o0, uint32_t* o1) {
  const uint32_t ks0 = k0, ks1 = k1, ks2 = k0 ^ k1 ^ 0x1BD11BDAu;
  x0 += ks0; x1 += ks1;
#define TF_R(r) { x0 += x1; x1 = (x1 << (r)) | (x1 >> (32 - (r))); x1 ^= x0; }
  TF_R(13) TF_R(15) TF_R(26) TF_R(6)
  x0 += ks1; x1 += ks2 + 1u;
  TF_R(17) TF_R(29) TF_R(16) TF_R(24)
  x0 += ks2; x1 += ks0 + 2u;
  TF_R(13) TF_R(15) TF_R(26) TF_R(6)
  x0 += ks0; x1 += ks1 + 3u;
  TF_R(17) TF_R(29) TF_R(16) TF_R(24)
  x0 += ks1; x1 += ks2 + 4u;
  TF_R(13) TF_R(15) TF_R(26) TF_R(6)
  x0 += ks2; x1 += ks0 + 5u;
#undef TF_R
  *o0 = x0; *o1 = x1;
}

__device__ __forceinline__ double fast_log(double x) {
  long long ib = __double_as_longlong(x);
  int e = (int)((ib >> 52) & 0x7ff) - 1023;
  double r = __longlong_as_double((ib & 0xfffffffffffffLL) | 0x3ff0000000000000LL);
  if (r > 1.4142135623730951) { r *= 0.5; e += 1; }
  double s = (r - 1.0) / (r + 1.0);
  double s2 = s * s;
  double t = fma(s2, fma(s2, fma(s2, fma(s2, fma(s2, fma(s2,
      1.0/15.0, 1.0/13.0), 1.0/11.0), 1.0/9.0), 1.0/7.0), 1.0/5.0), 1.0/3.0);
  double lr = fma(2.0 * s * s2, t, 2.0 * s);
  return fma((double)e, 0.6931471805599453, lr);
}

__device__ __forceinline__ double fast_exp(double x) {
  double nd = rint(x * 1.4426950408889634);
  double f = fma(nd, -0.6931471803691238, x);
  f = fma(nd, -1.9082149292705877e-10, f);
  double p = 2.505210838544172e-8;
  p = fma(p, f, 2.755731922398589e-7);
  p = fma(p, f, 2.7557319223985893e-6);
  p = fma(p, f, 2.48015873015873e-5);
  p = fma(p, f, 1.984126984126984e-4);
  p = fma(p, f, 1.3888888888888889e-3);
  p = fma(p, f, 8.333333333333333e-3);
  p = fma(p, f, 4.1666666666666664e-2);
  p = fma(p, f, 0.16666666666666666);
  p = fma(p, f, 0.5);
  p = fma(p, f, 1.0);
  p = fma(p, f, 1.0);
  return ldexp(p, (int)nd);
}

__device__ __forceinline__ double gumbel_pool9(const double (&acc)[9],
                                               double bb, uint64_t base,
                                               uint32_t kp0, uint32_t kp1) {
  double bestv = -1e308, bA = 1.0, bQ = 0.0;
#pragma unroll
  for (int k = 0; k < 9; ++k) {
    double pre = (acc[k] + bb) * INV_SIGMA2;
    double q = fast_exp(-fabs(pre));
    double A = pre >= 0.0 ? 1.0 : q;          // p = A/(1+q)
    double opq = 1.0 + q;
    double L = fast_log(fma(EPS_D, opq, A)) - fast_log(opq);
    uint32_t o0, o1;
    uint64_t idx = base + (uint64_t)k;
    threefry2x32(kp0, kp1, (uint32_t)(idx >> 32), (uint32_t)idx, &o0, &o1);
    uint32_t bits = o0 ^ o1;
    float u = __uint_as_float((bits >> 9) | 0x3f800000u) - 1.0f;
    if (u == 0.0f) u = 1.17549435e-38f;
    float lg1 = (float)fast_log((double)u);
    double lg2 = fast_log(-(double)lg1);
    float gf = -(float)lg2;
    double v = L + (double)gf;
    if (v > bestv) { bestv = v; bA = A; bQ = q; }   // first-occurrence argmax
  }
  return bA / (1.0 + bQ);
}

// ---- l1: vertical output pair (unchanged from R8) ----
template <int LDSTRIDE, typename T>
__device__ __forceinline__ void conv_pair(const T* __restrict__ xb,
                                          const double (&w)[49],
                                          double (&a0)[9], double (&a1)[9]) {
#pragma unroll
  for (int pr = 0; pr < 12; ++pr) {
    double xr[9];
#pragma unroll
    for (int c = 0; c < 9; ++c) xr[c] = (double)xb[pr * LDSTRIDE + c];
#pragma unroll
    for (int ki = 0; ki < 3; ++ki) {
      const int u0 = pr - ki;
      if (u0 >= 0 && u0 <= 6) {
#pragma unroll
        for (int kj = 0; kj < 3; ++kj)
#pragma unroll
          for (int v = 0; v < 7; ++v)
            a0[ki * 3 + kj] = fma(xr[kj + v], w[u0 * 7 + v], a0[ki * 3 + kj]);
      }
      const int u1 = pr - 3 - ki;
      if (u1 >= 0 && u1 <= 6) {
#pragma unroll
        for (int kj = 0; kj < 3; ++kj)
#pragma unroll
          for (int v = 0; v < 7; ++v)
            a1[ki * 3 + kj] = fma(xr[kj + v], w[u1 * 7 + v], a1[ki * 3 + kj]);
      }
    }
  }
}

// ---- l2: 2x2 output quad, one patch row PR (literal). 12 xr doubles,
// outputs (r,c2): a_rc uses w row PR-3r-ki, cols xr[3*c2 + kj + v].
// Per-acc order: pr asc -> w-row asc, v asc == reference (kh,kw) order.
template <int PR>
__device__ __forceinline__ void quad_step(const double* __restrict__ xb,
                                          const double (&w)[49],
                                          double (&a00)[9], double (&a01)[9],
                                          double (&a10)[9], double (&a11)[9]) {
  double xr[12];
#pragma unroll
  for (int c = 0; c < 12; ++c) xr[c] = xb[PR * 30 + c];
#pragma unroll
  for (int ki = 0; ki < 3; ++ki) {
    const int u0 = PR - ki;
    if (u0 >= 0 && u0 <= 6) {
#pragma unroll
      for (int kj = 0; kj < 3; ++kj)
#pragma unroll
        for (int v = 0; v < 7; ++v) {
          a00[ki * 3 + kj] = fma(xr[kj + v],     w[u0 * 7 + v], a00[ki * 3 + kj]);
          a01[ki * 3 + kj] = fma(xr[3 + kj + v], w[u0 * 7 + v], a01[ki * 3 + kj]);
        }
    }
    const int u1 = PR - 3 - ki;
    if (u1 >= 0 && u1 <= 6) {
#pragma unroll
      for (int kj = 0; kj < 3; ++kj)
#pragma unroll
        for (int v = 0; v < 7; ++v) {
          a10[ki * 3 + kj] = fma(xr[kj + v],     w[u1 * 7 + v], a10[ki * 3 + kj]);
          a11[ki * 3 + kj] = fma(xr[3 + kj + v], w[u1 * 7 + v], a11[ki * 3 + kj]);
        }
    }
  }
}

#define QUAD_ALL(XB) \
  quad_step<0>((XB), w, a00, a01, a10, a11);  quad_step<1>((XB), w, a00, a01, a10, a11); \
  quad_step<2>((XB), w, a00, a01, a10, a11);  quad_step<3>((XB), w, a00, a01, a10, a11); \
  quad_step<4>((XB), w, a00, a01, a10, a11);  quad_step<5>((XB), w, a00, a01, a10, a11); \
  quad_step<6>((XB), w, a00, a01, a10, a11);  quad_step<7>((XB), w, a00, a01, a10, a11); \
  quad_step<8>((XB), w, a00, a01, a10, a11);  quad_step<9>((XB), w, a00, a01, a10, a11); \
  quad_step<10>((XB), w, a00, a01, a10, a11); quad_step<11>((XB), w, a00, a01, a10, a11);

// ---------------- Layer 1 ---------------- (unchanged from R8)
__global__ __launch_bounds__(256, 3) void l1_kernel(
    const float* __restrict__ x, const float* __restrict__ W1,
    const float* __restrict__ b1, double* __restrict__ h1,
    uint32_t kp0, uint32_t kp1) {
  const int oc   = blockIdx.x;   // 96
  const int b    = blockIdx.y;   // 64
  const int half = blockIdx.z;   // 2
  const int t = threadIdx.x;
  const int wave = t >> 6;

  __shared__ float xs[54 * 96];   // 20,736 B

  const int p0 = 14 * half;
  const bool active = t < 240;
  const int q = t / 30, bw = t - q * 30;   // q 0..7 vertical pair
  const float* xb = xs + (6 * q) * 96 + 3 * bw;

  double a0[9] = {}, a1[9] = {};
  double w[49];

#pragma unroll 1
  for (int ic = 0; ic < 3; ++ic) {
    __syncthreads();   // readers of previous ic done
    {
      const char* gsrc = (const char*)(x + ((size_t)b * 3 + ic) * 9216 + (3 * p0) * 96);
#pragma unroll
      for (int p = 0; p < 6; ++p) {
        int elt = p * 256 + t;
        if (elt < 1296) {
          __builtin_amdgcn_global_load_lds(
              (const __attribute__((address_space(1))) void*)(gsrc + (size_t)elt * 16),
              (__attribute__((address_space(3))) void*)((char*)xs +
                                                        (size_t)(p * 256 + wave * 64) * 16),
              16, 0, 0);
        }
      }
    }
    __syncthreads();   // DMA drained
    {
      const float* __restrict__ wsrc = W1 + (oc * 3 + ic) * 49;  // block-uniform
#pragma unroll
      for (int j = 0; j < 49; ++j) w[j] = (double)wsrc[j];
    }
    if (active) conv_pair<96, float>(xb, w, a0, a1);
  }

  if (active) {
    const double bb = (double)b1[oc];
    const int bh0 = p0 + 2 * q;
#pragma unroll
    for (int j = 0; j < 2; ++j) {
      const int pos = (bh0 + j) * 30 + bw;
      const uint64_t base = ((uint64_t)((b * 96 + oc) * 900 + pos)) * 9ull;
      double pooled = gumbel_pool9(j ? a1 : a0, bb, base, kp0, kp1);
      h1[(size_t)(b * 96 + oc) * 900 + pos] = pooled;
    }
  }
}

// ---------------- Layer 2 ----------------
// Block = (oc-tile of 16, b); 256 threads = 16 oc x 16 sb, each thread a 2x2
// pooled quad. Wave = 4 oc x 16 sb; quarter-wave = 2 oc x 8 sb of one parity
// group (sb_h = 2*(sb>>2)+group): hs addresses: 2 lanes/sb identical
// (broadcast) + 8 distinct even bank-pair residues -> conflict-free (b128's
// 2-pair span covers all 16). ic-chunk 1 double-buffered: hs via 16B
// global_load_lds DMA, wsd f64 in LDS. LDS 26.9 KB.
__global__ __launch_bounds__(256, 2) void l2_kernel(
    const double* __restrict__ h1, const float* __restrict__ W2,
    const float* __restrict__ b2, float* __restrict__ out,
    uint32_t kp0, uint32_t kp1) {
  const int octile = blockIdx.x;  // 12
  const int b      = blockIdx.y;  // 64
  const int t = threadIdx.x;
  const int wave = t >> 6, li = t & 63;
  const int duo    = (li >> 5) & 1;
  const int group  = (li >> 4) & 1;
  const int oc_sel = (li >> 3) & 1;
  const int sb     = li & 7;
  const int sb_h = 2 * (sb >> 2) + group;   // {0,2}+group -> 0..3
  const int sb_w = sb & 3;
  const int oc_local = wave * 4 + duo * 2 + oc_sel;   // 0..15
  const int oc = octile * 16 + oc_local;
  const int bh0 = 2 * sb_h, bw0 = 2 * sb_w;

  __shared__ double hs[2][900];     // 14,400 B
  __shared__ double wsd[2][784];    // 12,544 B  (16 oc x 49, f64)

  const double* __restrict__ hb = h1 + (size_t)b * 86400;
  const float* __restrict__ wg = W2 + (size_t)octile * 16 * 4704;

  double a00[9] = {}, a01[9] = {}, a10[9] = {}, a11[9] = {};
  double w[49];

  auto stage = [&](int c, int buf) {
    // hs: 900 doubles = 450 x 16B contiguous; DMA dest = wave base + lane*16.
    const char* gsrc = (const char*)(hb + (size_t)c * 900);
#pragma unroll
    for (int p = 0; p < 2; ++p) {
      int elt = p * 256 + t;
      if (elt < 450) {
        __builtin_amdgcn_global_load_lds(
            (const __attribute__((address_space(1))) void*)(gsrc + (size_t)elt * 16),
            (__attribute__((address_space(3))) void*)((char*)&hs[buf][0] +
                                                      (size_t)(p * 256 + wave * 64) * 16),
            16, 0, 0);
      }
    }
    // weights: 16 oc x 49 f32 -> f64, layout [oi][j].
#pragma unroll
    for (int p = 0; p < 4; ++p) {
      int j = p * 256 + t;
      if (j < 784) {
        int oi = j / 49, rem = j - oi * 49;
        wsd[buf][j] = (double)wg[(size_t)oi * 4704 + c * 49 + rem];
      }
    }
  };

  stage(0, 0);
#pragma unroll 1
  for (int c = 0; c < 96; ++c) {
    __syncthreads();   // drains DMA for buf c&1; all waves done with other buf
    if (c + 1 < 96) stage(c + 1, (c + 1) & 1);
    {
      const double* __restrict__ wsrc = &wsd[c & 1][oc_local * 49];
#pragma unroll
      for (int j = 0; j < 49; ++j) w[j] = wsrc[j];   // LDS bcast (2 addr/qwave)
      const double* xb = &hs[c & 1][(6 * sb_h) * 30 + 6 * sb_w];
      QUAD_ALL(xb)
    }
  }

  const double bb = (double)b2[oc];
  const double* accs[4] = {a00, a01, a10, a11};
#pragma unroll
  for (int r = 0; r < 2; ++r)
#pragma unroll
    for (int c2 = 0; c2 < 2; ++c2) {
      const int bh = bh0 + r, bwp = bw0 + c2;
      const uint64_t base = ((uint64_t)(((b * 192 + oc) * 8 + bh) * 8 + bwp)) * 9ull;
      const double (&ar)[9] = *(const double (*)[9])accs[r * 2 + c2];
      double pooled = gumbel_pool9(ar, bb, base, kp0, kp1);
      out[(size_t)(b * 192 + oc) * 64 + bh * 8 + bwp] = (float)pooled;
    }
}

extern "C" void kernel_launch(void* const* d_in, const int* in_sizes, int n_in,
                              void* d_out, int out_size, void* d_ws,
                              size_t ws_size, hipStream_t stream) {
  const float* x  = (const float*)d_in[0];   // [64,3,96,96]
  const float* W1 = (const float*)d_in[1];   // [96,3,7,7]
  const float* b1 = (const float*)d_in[2];   // [96]
  const float* W2 = (const float*)d_in[3];   // [192,96,7,7]
  const float* b2 = (const float*)d_in[4];   // [192]
  float* out = (float*)d_out;                // [64,192,8,8]
  double* h1 = (double*)d_ws;                // 5,529,600 f64 = 44.2 MB

  uint32_t kp1a, kp1b, kp2a, kp2b;
  threefry2x32(0u, 42u, 0u, 0u, &kp1a, &kp1b);
  threefry2x32(0u, 42u, 0u, 1u, &kp2a, &kp2b);

  l1_kernel<<<dim3(96, 64, 2), 256, 0, stream>>>(x, W1, b1, h1, kp1a, kp1b);
  l2_kernel<<<dim3(12, 64), 256, 0, stream>>>(h1, W2, b2, out, kp2a, kp2b);
}

// Round 12
// 1838.847 us; speedup vs baseline: 3.6996x; 1.0658x over previous
//
#include <hip/hip_runtime.h>
#include <cstdint>
#include <math.h>

// ConvDBN: 2-layer conv-RBM with Gumbel-max multinomial pooling.
// Numerics: l1 + fallback-l2 + redo in exact f64 (verified R1-R9, absmax
// 0.0039, zero flips); RNG: JAX threefry2x32 partitionable split (child i =
// threefry(key,(0,i))), 32-bit draw = o0^o1, gumbel f32 rounding points exact.
// R12: R10/R11 failed from a STAGING BUG, not numerics: weight staging was a
// single 256-thread pass over 392 elements -> LDS weights 256..391 held 0xAA
// poison -> 3 of 8 oc garbage (absmax 1.0). Fixed: 2-pass staging everywhere.
// Mixed scheme kept (R11): per-ic f32 chunks (err ~2e-7) folded into f64 acc
// ic-ascending -> score err ~5e-5 rms, max ~3e-4 over 7.1M; pool + top-2 gap
// exact-f64 on f64 acc, TAU=6e-3 (20x max err); flagged (~0.6%, ~4.7k <<
// 32768 cap) redone in exact f64 from h1_f64 (redo == ref within 1e-15).
// NEW: l1 dual-stores h1 f32 (bit-identical to cvt-on-read); l2-main stages
// f32 (half LDS bytes). Bank check (b32): quarter-wave residues {3bw}u{3bw+8}
// (and +20/+28): 3*dbw==8 mod 32 unsolvable for |dbw|<=7 => 16 distinct
// banks/quarter => conflict-free. Tiered ws guard (launch-constant):
// full(66.5MB) -> mid(44.4MB, f64-staged mixed) -> low (pure-f64 R8).

#define EPS_D 1e-8
#define INV_SIGMA2 (1.0 / (0.2 * 0.2))
#define TAU 6e-3
#define REDO_CAP 32768
#define H1_BYTES (5529600ull * 8ull)
#define H1F32_BYTES (5529600ull * 4ull)

__host__ __device__ __forceinline__ void threefry2x32(
    uint32_t k0, uint32_t k1, uint32_t x0, uint32_t x1,
    uint32_t* o0, uint32_t* o1) {
  const uint32_t ks0 = k0, ks1 = k1, ks2 = k0 ^ k1 ^ 0x1BD11BDAu;
  x0 += ks0; x1 += ks1;
#define TF_R(r) { x0 += x1; x1 = (x1 << (r)) | (x1 >> (32 - (r))); x1 ^= x0; }
  TF_R(13) TF_R(15) TF_R(26) TF_R(6)
  x0 += ks1; x1 += ks2 + 1u;
  TF_R(17) TF_R(29) TF_R(16) TF_R(24)
  x0 += ks2; x1 += ks0 + 2u;
  TF_R(13) TF_R(15) TF_R(26) TF_R(6)
  x0 += ks0; x1 += ks1 + 3u;
  TF_R(17) TF_R(29) TF_R(16) TF_R(24)
  x0 += ks1; x1 += ks2 + 4u;
  TF_R(13) TF_R(15) TF_R(26) TF_R(6)
  x0 += ks2; x1 += ks0 + 5u;
#undef TF_R
  *o0 = x0; *o1 = x1;
}

__device__ __forceinline__ double fast_log(double x) {
  long long ib = __double_as_longlong(x);
  int e = (int)((ib >> 52) & 0x7ff) - 1023;
  double r = __longlong_as_double((ib & 0xfffffffffffffLL) | 0x3ff0000000000000LL);
  if (r > 1.4142135623730951) { r *= 0.5; e += 1; }
  double s = (r - 1.0) / (r + 1.0);
  double s2 = s * s;
  double t = fma(s2, fma(s2, fma(s2, fma(s2, fma(s2, fma(s2,
      1.0/15.0, 1.0/13.0), 1.0/11.0), 1.0/9.0), 1.0/7.0), 1.0/5.0), 1.0/3.0);
  double lr = fma(2.0 * s * s2, t, 2.0 * s);
  return fma((double)e, 0.6931471805599453, lr);
}

__device__ __forceinline__ double fast_exp(double x) {
  double nd = rint(x * 1.4426950408889634);
  double f = fma(nd, -0.6931471803691238, x);
  f = fma(nd, -1.9082149292705877e-10, f);
  double p = 2.505210838544172e-8;
  p = fma(p, f, 2.755731922398589e-7);
  p = fma(p, f, 2.7557319223985893e-6);
  p = fma(p, f, 2.48015873015873e-5);
  p = fma(p, f, 1.984126984126984e-4);
  p = fma(p, f, 1.3888888888888889e-3);
  p = fma(p, f, 8.333333333333333e-3);
  p = fma(p, f, 4.1666666666666664e-2);
  p = fma(p, f, 0.16666666666666666);
  p = fma(p, f, 0.5);
  p = fma(p, f, 1.0);
  p = fma(p, f, 1.0);
  return ldexp(p, (int)nd);
}

__device__ __forceinline__ double gumbel_pool9(const double (&acc)[9],
                                               double bb, uint64_t base,
                                               uint32_t kp0, uint32_t kp1) {
  double bestv = -1e308, bA = 1.0, bQ = 0.0;
#pragma unroll
  for (int k = 0; k < 9; ++k) {
    double pre = (acc[k] + bb) * INV_SIGMA2;
    double q = fast_exp(-fabs(pre));
    double A = pre >= 0.0 ? 1.0 : q;          // p = A/(1+q)
    double opq = 1.0 + q;
    double L = fast_log(fma(EPS_D, opq, A)) - fast_log(opq);
    uint32_t o0, o1;
    uint64_t idx = base + (uint64_t)k;
    threefry2x32(kp0, kp1, (uint32_t)(idx >> 32), (uint32_t)idx, &o0, &o1);
    uint32_t bits = o0 ^ o1;
    float u = __uint_as_float((bits >> 9) | 0x3f800000u) - 1.0f;
    if (u == 0.0f) u = 1.17549435e-38f;
    float lg1 = (float)fast_log((double)u);
    double lg2 = fast_log(-(double)lg1);
    float gf = -(float)lg2;
    double v = L + (double)gf;
    if (v > bestv) { bestv = v; bA = A; bQ = q; }   // first-occurrence argmax
  }
  return bA / (1.0 + bQ);
}

__device__ __forceinline__ double gumbel_pool9_gap(const double (&acc)[9],
                                                   double bb, uint64_t base,
                                                   uint32_t kp0, uint32_t kp1,
                                                   double* gap) {
  double bestv = -1e308, second = -1e308, bA = 1.0, bQ = 0.0;
#pragma unroll
  for (int k = 0; k < 9; ++k) {
    double pre = (acc[k] + bb) * INV_SIGMA2;
    double q = fast_exp(-fabs(pre));
    double A = pre >= 0.0 ? 1.0 : q;
    double opq = 1.0 + q;
    double L = fast_log(fma(EPS_D, opq, A)) - fast_log(opq);
    uint32_t o0, o1;
    uint64_t idx = base + (uint64_t)k;
    threefry2x32(kp0, kp1, (uint32_t)(idx >> 32), (uint32_t)idx, &o0, &o1);
    uint32_t bits = o0 ^ o1;
    float u = __uint_as_float((bits >> 9) | 0x3f800000u) - 1.0f;
    if (u == 0.0f) u = 1.17549435e-38f;
    float lg1 = (float)fast_log((double)u);
    double lg2 = fast_log(-(double)lg1);
    float gf = -(float)lg2;
    double v = L + (double)gf;
    if (v > bestv) { second = bestv; bestv = v; bA = A; bQ = q; }
    else if (v > second) second = v;
  }
  *gap = bestv - second;
  return bA / (1.0 + bQ);
}

// ---- f64 vertical output pair (l1 + fallback l2; R8-verified) ----
template <int LDSTRIDE, typename T>
__device__ __forceinline__ void conv_pair(const T* __restrict__ xb,
                                          const double (&w)[49],
                                          double (&a0)[9], double (&a1)[9]) {
#pragma unroll
  for (int pr = 0; pr < 12; ++pr) {
    double xr[9];
#pragma unroll
    for (int c = 0; c < 9; ++c) xr[c] = (double)xb[pr * LDSTRIDE + c];
#pragma unroll
    for (int ki = 0; ki < 3; ++ki) {
      const int u0 = pr - ki;
      if (u0 >= 0 && u0 <= 6) {
#pragma unroll
        for (int kj = 0; kj < 3; ++kj)
#pragma unroll
          for (int v = 0; v < 7; ++v)
            a0[ki * 3 + kj] = fma(xr[kj + v], w[u0 * 7 + v], a0[ki * 3 + kj]);
      }
      const int u1 = pr - 3 - ki;
      if (u1 >= 0 && u1 <= 6) {
#pragma unroll
        for (int kj = 0; kj < 3; ++kj)
#pragma unroll
          for (int v = 0; v < 7; ++v)
            a1[ki * 3 + kj] = fma(xr[kj + v], w[u1 * 7 + v], a1[ki * 3 + kj]);
      }
    }
  }
}

// ---- mixed: one ic chunk in f32, folded into f64 acc (order preserved) ----
template <typename T>
__device__ __forceinline__ void conv_pair_f32c(const T* __restrict__ xb,
                                               const float (&w)[49],
                                               double (&A0)[9], double (&A1)[9]) {
  float c0[9] = {}, c1[9] = {};
#pragma unroll
  for (int pr = 0; pr < 12; ++pr) {
    float xr[9];
#pragma unroll
    for (int c = 0; c < 9; ++c) xr[c] = (float)xb[pr * 30 + c];
#pragma unroll
    for (int ki = 0; ki < 3; ++ki) {
      const int u0 = pr - ki;
      if (u0 >= 0 && u0 <= 6) {
#pragma unroll
        for (int kj = 0; kj < 3; ++kj)
#pragma unroll
          for (int v = 0; v < 7; ++v)
            c0[ki * 3 + kj] = fmaf(xr[kj + v], w[u0 * 7 + v], c0[ki * 3 + kj]);
      }
      const int u1 = pr - 3 - ki;
      if (u1 >= 0 && u1 <= 6) {
#pragma unroll
        for (int kj = 0; kj < 3; ++kj)
#pragma unroll
          for (int v = 0; v < 7; ++v)
            c1[ki * 3 + kj] = fmaf(xr[kj + v], w[u1 * 7 + v], c1[ki * 3 + kj]);
      }
    }
  }
#pragma unroll
  for (int k = 0; k < 9; ++k) { A0[k] += (double)c0[k]; A1[k] += (double)c1[k]; }
}

// ---------------- Layer 1 (f64, R8-verified; optional f32 shadow store) ----
__global__ __launch_bounds__(256, 3) void l1_kernel(
    const float* __restrict__ x, const float* __restrict__ W1,
    const float* __restrict__ b1, double* __restrict__ h1,
    float* __restrict__ h1f32, int write_f32,
    uint32_t kp0, uint32_t kp1) {
  const int oc   = blockIdx.x;   // 96
  const int b    = blockIdx.y;   // 64
  const int half = blockIdx.z;   // 2
  const int t = threadIdx.x;
  const int wave = t >> 6;

  __shared__ float xs[54 * 96];   // 20,736 B

  const int p0 = 14 * half;
  const bool active = t < 240;
  const int q = t / 30, bw = t - q * 30;
  const float* xb = xs + (6 * q) * 96 + 3 * bw;

  double a0[9] = {}, a1[9] = {};
  double w[49];

#pragma unroll 1
  for (int ic = 0; ic < 3; ++ic) {
    __syncthreads();
    {
      const char* gsrc = (const char*)(x + ((size_t)b * 3 + ic) * 9216 + (3 * p0) * 96);
#pragma unroll
      for (int p = 0; p < 6; ++p) {
        int elt = p * 256 + t;
        if (elt < 1296) {
          __builtin_amdgcn_global_load_lds(
              (const __attribute__((address_space(1))) void*)(gsrc + (size_t)elt * 16),
              (__attribute__((address_space(3))) void*)((char*)xs +
                                                        (size_t)(p * 256 + wave * 64) * 16),
              16, 0, 0);
        }
      }
    }
    __syncthreads();
    {
      const float* __restrict__ wsrc = W1 + (oc * 3 + ic) * 49;
#pragma unroll
      for (int j = 0; j < 49; ++j) w[j] = (double)wsrc[j];
    }
    if (active) conv_pair<96, float>(xb, w, a0, a1);
  }

  if (active) {
    const double bb = (double)b1[oc];
    const int bh0 = p0 + 2 * q;
#pragma unroll
    for (int j = 0; j < 2; ++j) {
      const int pos = (bh0 + j) * 30 + bw;
      const uint64_t base = ((uint64_t)((b * 96 + oc) * 900 + pos)) * 9ull;
      double pooled = gumbel_pool9(j ? a1 : a0, bb, base, kp0, kp1);
      const size_t oidx = (size_t)(b * 96 + oc) * 900 + pos;
      h1[oidx] = pooled;
      if (write_f32) h1f32[oidx] = (float)pooled;  // == cvt-on-read, bitwise
    }
  }
}

__global__ void init_kernel(unsigned int* cnt) {
  if (threadIdx.x == 0 && blockIdx.x == 0) *cnt = 0u;
}

// ---------------- Layer 2 main: mixed, f32-staged hs ----------------
__global__ __launch_bounds__(256, 3) void l2_kernel_mixed32(
    const float* __restrict__ h1f32, const float* __restrict__ W2,
    const float* __restrict__ b2, float* __restrict__ out,
    unsigned int* __restrict__ cnt, unsigned int* __restrict__ list,
    uint32_t kp0, uint32_t kp1) {
  const int octile = blockIdx.x;  // 24
  const int b      = blockIdx.y;  // 64
  const int t = threadIdx.x;
  const int wave = t >> 6;
  const int oc_local = t >> 5;
  const int li = t & 31;
  const int bw = li & 7;
  const int ph = 2 * ((li >> 3) & 1) + (li >> 4);
  const int bh0 = 2 * ph;
  const int oc = octile * 8 + oc_local;

  __shared__ float hs[2][900];      // 7,200 B
  __shared__ float wsf[2][392];     // 3,136 B

  const float* __restrict__ hb = h1f32 + (size_t)b * 86400;
  const float* __restrict__ wg = W2 + (size_t)octile * 8 * 4704;

  double a0[9] = {}, a1[9] = {};
  float w[49];

  auto stage = [&](int c, int buf) {
    const char* gsrc = (const char*)(hb + (size_t)c * 900);
    if (t < 225) {    // 900 f32 = 225 x 16B, contiguous
      __builtin_amdgcn_global_load_lds(
          (const __attribute__((address_space(1))) void*)(gsrc + (size_t)t * 16),
          (__attribute__((address_space(3))) void*)((char*)&hs[buf][0] +
                                                    (size_t)(wave * 64) * 16),
          16, 0, 0);
    }
#pragma unroll
    for (int p = 0; p < 2; ++p) {   // TWO passes: 392 > 256 (the R10/R11 fix)
      int j = p * 256 + t;
      if (j < 392) {
        int oi = j / 49, rem = j - oi * 49;
        wsf[buf][j] = wg[(size_t)oi * 4704 + c * 49 + rem];
      }
    }
  };

  stage(0, 0);
#pragma unroll 1
  for (int c = 0; c < 96; ++c) {
    __syncthreads();
    if (c + 1 < 96) stage(c + 1, (c + 1) & 1);
    {
      const float* __restrict__ wsrc = &wsf[c & 1][oc_local * 49];
#pragma unroll
      for (int j = 0; j < 49; ++j) w[j] = wsrc[j];
      const float* xb = &hs[c & 1][(6 * ph) * 30 + 3 * bw];
      conv_pair_f32c<float>(xb, w, a0, a1);
    }
  }

  const double bb = (double)b2[oc];
#pragma unroll
  for (int j = 0; j < 2; ++j) {
    const int bh = bh0 + j;
    const unsigned int oid = (unsigned int)((b * 192 + oc) * 64 + bh * 8 + bw);
    const uint64_t base = (uint64_t)oid * 9ull;
    double gap;
    double pooled = gumbel_pool9_gap(j ? a1 : a0, bb, base, kp0, kp1, &gap);
    out[oid] = (float)pooled;
    if (gap < TAU) {
      unsigned int idx = atomicAdd(cnt, 1u);
      if (idx < REDO_CAP) list[idx] = oid;
    }
  }
}

// ---------------- Layer 2 mid: mixed, f64-staged hs ----------------
__global__ __launch_bounds__(256, 3) void l2_kernel_mixed64(
    const double* __restrict__ h1, const float* __restrict__ W2,
    const float* __restrict__ b2, float* __restrict__ out,
    unsigned int* __restrict__ cnt, unsigned int* __restrict__ list,
    uint32_t kp0, uint32_t kp1) {
  const int octile = blockIdx.x;
  const int b      = blockIdx.y;
  const int t = threadIdx.x;
  const int wave = t >> 6;
  const int oc_local = t >> 5;
  const int li = t & 31;
  const int bw = li & 7;
  const int ph = 2 * ((li >> 3) & 1) + (li >> 4);
  const int bh0 = 2 * ph;
  const int oc = octile * 8 + oc_local;

  __shared__ double hs[2][900];
  __shared__ float  wsf[2][392];

  const double* __restrict__ hb = h1 + (size_t)b * 86400;
  const float* __restrict__ wg = W2 + (size_t)octile * 8 * 4704;

  double a0[9] = {}, a1[9] = {};
  float w[49];

  auto stage = [&](int c, int buf) {
    const char* gsrc = (const char*)(hb + (size_t)c * 900);
#pragma unroll
    for (int p = 0; p < 2; ++p) {
      int elt = p * 256 + t;
      if (elt < 450) {
        __builtin_amdgcn_global_load_lds(
            (const __attribute__((address_space(1))) void*)(gsrc + (size_t)elt * 16),
            (__attribute__((address_space(3))) void*)((char*)&hs[buf][0] +
                                                      (size_t)(p * 256 + wave * 64) * 16),
            16, 0, 0);
      }
    }
#pragma unroll
    for (int p = 0; p < 2; ++p) {   // TWO passes
      int j = p * 256 + t;
      if (j < 392) {
        int oi = j / 49, rem = j - oi * 49;
        wsf[buf][j] = wg[(size_t)oi * 4704 + c * 49 + rem];
      }
    }
  };

  stage(0, 0);
#pragma unroll 1
  for (int c = 0; c < 96; ++c) {
    __syncthreads();
    if (c + 1 < 96) stage(c + 1, (c + 1) & 1);
    {
      const float* __restrict__ wsrc = &wsf[c & 1][oc_local * 49];
#pragma unroll
      for (int j = 0; j < 49; ++j) w[j] = wsrc[j];
      const double* xb = &hs[c & 1][(6 * ph) * 30 + 3 * bw];
      conv_pair_f32c<double>(xb, w, a0, a1);
    }
  }

  const double bb = (double)b2[oc];
#pragma unroll
  for (int j = 0; j < 2; ++j) {
    const int bh = bh0 + j;
    const unsigned int oid = (unsigned int)((b * 192 + oc) * 64 + bh * 8 + bw);
    const uint64_t base = (uint64_t)oid * 9ull;
    double gap;
    double pooled = gumbel_pool9_gap(j ? a1 : a0, bb, base, kp0, kp1, &gap);
    out[oid] = (float)pooled;
    if (gap < TAU) {
      unsigned int idx = atomicAdd(cnt, 1u);
      if (idx < REDO_CAP) list[idx] = oid;
    }
  }
}

// ---------------- Layer 2 fallback (pure f64, R8-verified) ----------------
__global__ __launch_bounds__(256, 3) void l2_kernel_f64(
    const double* __restrict__ h1, const float* __restrict__ W2,
    const float* __restrict__ b2, float* __restrict__ out,
    uint32_t kp0, uint32_t kp1) {
  const int octile = blockIdx.x;
  const int b      = blockIdx.y;
  const int t = threadIdx.x;
  const int wave = t >> 6;
  const int oc_local = t >> 5;
  const int li = t & 31;
  const int bw = li & 7;
  const int ph = 2 * ((li >> 3) & 1) + (li >> 4);
  const int bh0 = 2 * ph;
  const int oc = octile * 8 + oc_local;

  __shared__ double hs[2][900];
  __shared__ double wsd[2][392];

  const double* __restrict__ hb = h1 + (size_t)b * 86400;
  const float* __restrict__ wg = W2 + (size_t)octile * 8 * 4704;

  double a0[9] = {}, a1[9] = {};
  double w[49];

  auto stage = [&](int c, int buf) {
    const char* gsrc = (const char*)(hb + (size_t)c * 900);
#pragma unroll
    for (int p = 0; p < 2; ++p) {
      int elt = p * 256 + t;
      if (elt < 450) {
        __builtin_amdgcn_global_load_lds(
            (const __attribute__((address_space(1))) void*)(gsrc + (size_t)elt * 16),
            (__attribute__((address_space(3))) void*)((char*)&hs[buf][0] +
                                                      (size_t)(p * 256 + wave * 64) * 16),
            16, 0, 0);
      }
    }
#pragma unroll
    for (int p = 0; p < 2; ++p) {   // TWO passes
      int j = p * 256 + t;
      if (j < 392) {
        int oi = j / 49, rem = j - oi * 49;
        wsd[buf][j] = (double)wg[(size_t)oi * 4704 + c * 49 + rem];
      }
    }
  };

  stage(0, 0);
#pragma unroll 1
  for (int c = 0; c < 96; ++c) {
    __syncthreads();
    if (c + 1 < 96) stage(c + 1, (c + 1) & 1);
    {
      const double* __restrict__ wsrc = &wsd[c & 1][oc_local * 49];
#pragma unroll
      for (int j = 0; j < 49; ++j) w[j] = wsrc[j];
      const double* xb = &hs[c & 1][(6 * ph) * 30 + 3 * bw];
      conv_pair<30, double>(xb, w, a0, a1);
    }
  }

  const double bb = (double)b2[oc];
#pragma unroll
  for (int j = 0; j < 2; ++j) {
    const int bh = bh0 + j;
    const uint64_t base = ((uint64_t)(((b * 192 + oc) * 8 + bh) * 8 + bw)) * 9ull;
    double pooled = gumbel_pool9(j ? a1 : a0, bb, base, kp0, kp1);
    out[(size_t)(b * 192 + oc) * 64 + bh * 8 + bw] = (float)pooled;
  }
}

// ---------------- Layer 2 tie-redo (exact f64 from h1_f64) ----------------
__global__ __launch_bounds__(64) void l2_redo_kernel(
    const double* __restrict__ h1, const float* __restrict__ W2,
    const float* __restrict__ b2, float* __restrict__ out,
    const unsigned int* __restrict__ cnt, const unsigned int* __restrict__ list,
    uint32_t kp0, uint32_t kp1) {
  unsigned int n = *cnt;
  if (n > REDO_CAP) n = REDO_CAP;
  if (blockIdx.x >= n) return;
  const unsigned int oid = list[blockIdx.x];
  const int sp = oid & 63, bh = sp >> 3, bw = sp & 7;
  const int rest = oid >> 6, oc = rest % 192, b = rest / 192;
  const int lane = threadIdx.x;

  double acc[9] = {};
  for (int ic = lane; ic < 96; ic += 64) {
    const double* __restrict__ xp =
        h1 + ((size_t)(b * 96 + ic) * 30 + 3 * bh) * 30 + 3 * bw;
    const float* __restrict__ wp = W2 + ((size_t)oc * 96 + ic) * 49;
    double w[49];
#pragma unroll
    for (int j = 0; j < 49; ++j) w[j] = (double)wp[j];
#pragma unroll
    for (int pr = 0; pr < 9; ++pr) {
      double xr[9];
#pragma unroll
      for (int c = 0; c < 9; ++c) xr[c] = xp[pr * 30 + c];
#pragma unroll
      for (int kh = 0; kh < 3; ++kh) {
        const int u = pr - kh;
        if (u >= 0 && u <= 6) {
#pragma unroll
          for (int kw = 0; kw < 3; ++kw)
#pragma unroll
            for (int v = 0; v < 7; ++v)
              acc[kh * 3 + kw] = fma(xr[kw + v], w[u * 7 + v], acc[kh * 3 + kw]);
        }
      }
    }
  }
#pragma unroll
  for (int off = 32; off; off >>= 1)
#pragma unroll
    for (int k = 0; k < 9; ++k) acc[k] += __shfl_down(acc[k], off);

  if (lane == 0) {
    const uint64_t base = (uint64_t)oid * 9ull;
    double pooled = gumbel_pool9(acc, (double)b2[oc], base, kp0, kp1);
    out[oid] = (float)pooled;
  }
}

extern "C" void kernel_launch(void* const* d_in, const int* in_sizes, int n_in,
                              void* d_out, int out_size, void* d_ws,
                              size_t ws_size, hipStream_t stream) {
  const float* x  = (const float*)d_in[0];   // [64,3,96,96]
  const float* W1 = (const float*)d_in[1];   // [96,3,7,7]
  const float* b1 = (const float*)d_in[2];   // [96]
  const float* W2 = (const float*)d_in[3];   // [192,96,7,7]
  const float* b2 = (const float*)d_in[4];   // [192]
  float* out = (float*)d_out;                // [64,192,8,8]
  double* h1   = (double*)d_ws;              // 44.24 MB f64
  float* h1f32 = (float*)((char*)d_ws + H1_BYTES);  // 22.12 MB f32 (full tier)

  uint32_t kp1a, kp1b, kp2a, kp2b;
  threefry2x32(0u, 42u, 0u, 0u, &kp1a, &kp1b);
  threefry2x32(0u, 42u, 0u, 1u, &kp2a, &kp2b);

  const size_t need_full = H1_BYTES + H1F32_BYTES + 16 + (size_t)REDO_CAP * 4;
  const size_t need_mid  = H1_BYTES + 16 + (size_t)REDO_CAP * 4;

  if (ws_size >= need_full) {          // launch-constant branches: graph-safe
    unsigned int* cnt  = (unsigned int*)((char*)d_ws + H1_BYTES + H1F32_BYTES);
    unsigned int* list = cnt + 4;
    l1_kernel<<<dim3(96, 64, 2), 256, 0, stream>>>(x, W1, b1, h1, h1f32, 1,
                                                   kp1a, kp1b);
    init_kernel<<<1, 64, 0, stream>>>(cnt);
    l2_kernel_mixed32<<<dim3(24, 64), 256, 0, stream>>>(h1f32, W2, b2, out,
                                                        cnt, list, kp2a, kp2b);
    l2_redo_kernel<<<REDO_CAP, 64, 0, stream>>>(h1, W2, b2, out, cnt, list,
                                                kp2a, kp2b);
  } else if (ws_size >= need_mid) {
    unsigned int* cnt  = (unsigned int*)((char*)d_ws + H1_BYTES);
    unsigned int* list = cnt + 4;
    l1_kernel<<<dim3(96, 64, 2), 256, 0, stream>>>(x, W1, b1, h1, h1f32, 0,
                                                   kp1a, kp1b);
    init_kernel<<<1, 64, 0, stream>>>(cnt);
    l2_kernel_mixed64<<<dim3(24, 64), 256, 0, stream>>>(h1, W2, b2, out,
                                                        cnt, list, kp2a, kp2b);
    l2_redo_kernel<<<REDO_CAP, 64, 0, stream>>>(h1, W2, b2, out, cnt, list,
                                                kp2a, kp2b);
  } else {
    l1_kernel<<<dim3(96, 64, 2), 256, 0, stream>>>(x, W1, b1, h1, h1f32, 0,
                                                   kp1a, kp1b);
    l2_kernel_f64<<<dim3(24, 64), 256, 0, stream>>>(h1, W2, b2, out,
                                                    kp2a, kp2b);
  }
}